// Round 6
// baseline (107.719 us; speedup 1.0000x reference)
//
#include <hip/hip_runtime.h>
#include <math.h>

// Problem constants
#define NB    256           // N nodes
#define FINN  32            // Fin
#define FOUTN 32            // Fout
#define BT    128           // B*T

// One GEMM: C[i,(bt,o)] = H[i,(e,j)] @ y2[(e,j),(bt,o)],  M=256 N=4096 K=4096.
// v6 blocking: block = (2 bt, 2 e): grid (64,8) = 512 blocks, 2/CU.
// A-traffic halves to 128 MiB (theory: R2-R5 invariance = A-traffic bound).
// y2 produced in-LDS exactly once globally; B-frags fragment-linear;
// per wave: 2 i-tiles x 4 col-frags (8 MFMA : 4 ds_read balanced).
// f32 K-partials (8-way split, 32 MiB) -> verified epilogue.

typedef __attribute__((ext_vector_type(8))) short short8;   // 8 bf16 = 4 VGPRs
typedef __attribute__((ext_vector_type(4))) float floatx4;  // MFMA accumulator

#define MFMA16(a,b,c) __builtin_amdgcn_mfma_f32_16x16x32_bf16((a),(b),(c),0,0,0)

// LDS-ordering-only barrier: does NOT drain in-flight global register loads.
#define BARRIER() asm volatile("s_waitcnt lgkmcnt(0)\n\ts_barrier" ::: "memory")

__device__ __forceinline__ float gelu_f(float v) {
    return 0.5f * v * (1.0f + erff(v * 0.70710678118654752f));
}
__device__ __forceinline__ ushort f2bf(float x) {
    union { float f; unsigned u; } v; v.f = x;
    unsigned r = (v.u + 0x7FFFu + ((v.u >> 16) & 1u)) >> 16;
    return (ushort)r;
}
__device__ __forceinline__ uint2 pack4(floatx4 d) {
    uint2 p;
    p.x = (unsigned)f2bf(d[0]) | ((unsigned)f2bf(d[1]) << 16);
    p.y = (unsigned)f2bf(d[2]) | ((unsigned)f2bf(d[3]) << 16);
    return p;
}

// ---------------------------------------------------------------------------
// prep_kernel, grid 289 x 256 thr (verified rounds 2-5, verbatim):
//   [0,128):   Hf  = gelu(adj*w1+b1) in MFMA A-fragment order   (2 MiB)
//   [128,160): xaf = x in MFMA A-fragment order, bf16           (2 MiB)
//   [160,288): bias2g[bt][o] = node_b[o] + (sum_j x[bt,j,:]) @ b2
//   288:       w2f (B-frag order) + nwf (node_w B-frags)
// ---------------------------------------------------------------------------
__global__ __launch_bounds__(256) void prep_kernel(
        const float* __restrict__ x,   const float* __restrict__ adj,
        const float* __restrict__ w1,  const float* __restrict__ b1,
        const float* __restrict__ w2,  const float* __restrict__ b2,
        const float* __restrict__ node_w, const float* __restrict__ node_b,
        ushort* __restrict__ Hf, ushort* __restrict__ w2f,
        ushort* __restrict__ xaf, ushort* __restrict__ nwf,
        float* __restrict__ bias2g) {
    int bid = blockIdx.x;
    int tid = threadIdx.x;

    if (bid < 128) {                    // ---- Hf ----
        __shared__ float adjs[16][264];
        __shared__ float w1s[16], b1s[16];
        int it = bid & 15;
        int kq8 = bid >> 4;             // 0..7
        if (tid < 16) { w1s[tid] = w1[tid]; b1s[tid] = b1[tid]; }
        #pragma unroll
        for (int q = 0; q < 4; ++q) {
            int u = q * 256 + tid;
            int row = u >> 6, c4 = u & 63;
            *(float4*)&adjs[row][c4 * 4] =
                ((const float4*)(adj + ((size_t)it * 16 + row) * 256))[c4];
        }
        __syncthreads();
        #pragma unroll
        for (int q = 0; q < 4; ++q) {
            int u = q * 256 + tid;
            int ks = kq8 * 16 + (u >> 6);
            int lane = u & 63;
            int m = lane & 15, quad = lane >> 4;
            int e = ks >> 3;
            int j0 = (ks & 7) * 32 + quad * 8;
            float w = w1s[e], b = b1s[e];
            ushort tmp[8];
            #pragma unroll
            for (int d = 0; d < 8; ++d)
                tmp[d] = f2bf(gelu_f(adjs[m][j0 + d] * w + b));
            *(int4*)(Hf + (((size_t)it * 128 + ks) * 64 + lane) * 8) = *(int4*)tmp;
        }
        return;
    }
    if (bid < 160) {                    // ---- xaf: wave -> one bt ----
        int wv = tid >> 6, lane = tid & 63, m = lane & 15, quad = lane >> 4;
        int bt = (bid - 128) * 4 + wv;
        #pragma unroll
        for (int jt = 0; jt < 16; ++jt) {
            const float* xs = x + ((size_t)bt * NB + jt * 16 + m) * FINN + quad * 8;
            float4 lo = *(const float4*)xs;
            float4 hi = *(const float4*)(xs + 4);
            ushort tmp[8];
            tmp[0]=f2bf(lo.x); tmp[1]=f2bf(lo.y); tmp[2]=f2bf(lo.z); tmp[3]=f2bf(lo.w);
            tmp[4]=f2bf(hi.x); tmp[5]=f2bf(hi.y); tmp[6]=f2bf(hi.z); tmp[7]=f2bf(hi.w);
            *(int4*)(xaf + (((size_t)bt * 16 + jt) * 64 + lane) * 8) = *(int4*)tmp;
        }
        return;
    }
    if (bid < 288) {                    // ---- bias2g ----
        __shared__ float Sp[8][32];
        __shared__ float Svs[32];
        int bt = bid - 160;
        int f = tid & 31, grp = tid >> 5;
        float s = 0.f;
        for (int j = grp; j < NB; j += 8)
            s += x[((size_t)bt * NB + j) * FINN + f];
        Sp[grp][f] = s;
        __syncthreads();
        if (tid < 32) {
            float s2 = 0.f;
            #pragma unroll
            for (int g = 0; g < 8; ++g) s2 += Sp[g][tid];
            Svs[tid] = s2;
        }
        __syncthreads();
        if (tid < 32) {
            float bb = node_b[tid];
            #pragma unroll
            for (int f2 = 0; f2 < FINN; ++f2)
                bb += Svs[f2] * b2[f2 * FOUTN + tid];
            bias2g[bt * 32 + tid] = bb;
        }
        return;
    }
    // ---- bid == 288: w2f + nwf ----
    for (int s = 0; s < 2048; s += 256) {
        int slot = s + tid;             // (e*2+ot)*64 + lane
        int e = slot >> 7, r = slot & 127;
        int ot = r >> 6, lane = r & 63;
        int m = lane & 15, quad = lane >> 4;
        const float* src = w2 + (size_t)e * 1024 + (quad * 8) * 32 + ot * 16 + m;
        ushort tmp[8];
        #pragma unroll
        for (int i = 0; i < 8; ++i) tmp[i] = f2bf(src[i * 32]);
        *(int4*)(w2f + (size_t)slot * 8) = *(int4*)tmp;
    }
    if (tid < 128) {
        int ot = tid >> 6, lane = tid & 63, m = lane & 15, q = lane >> 4;
        ushort tmp[8];
        #pragma unroll
        for (int d = 0; d < 8; ++d)
            tmp[d] = f2bf(node_w[(q * 8 + d) * 32 + ot * 16 + m]);
        *(int4*)(nwf + tid * 8) = *(int4*)tmp;
    }
}

// ---------------------------------------------------------------------------
// main_kernel: grid (64 btg, 8 eq) x 512 thr (8 waves), 2 blocks/CU.
// Block: 256 i x 2 bt x 32 o x 2 e (16 ks). 2 windows (1 e each), dbuf.
// Produce: wave -> bt = wv&1, jt = (wv>>1)*4 + q (q<4), both oh: 8 MFMA +
// 8 ds_write per window (verified jt-generic scatter). Consume: wave ->
// it in {wv, wv+8}; per step: 2 A-ring refills, 4 linear ds_read_b128,
// 8 MFMA (all-independent acc[2][2][2]). Raw lgkm barriers keep the
// distance-4 A-ring in flight. Partials -> Cp f32 [bt][i][eq][o].
// ---------------------------------------------------------------------------
__global__ __launch_bounds__(512, 4) void main_kernel(
        const ushort* __restrict__ Hf,  const ushort* __restrict__ w2f,
        const ushort* __restrict__ xaf, float* __restrict__ Cp) {
    __shared__ ushort Bsl[2][2][8][2][512];   // 64 KiB [buf][bt][jp][oh][frag]

    int btg  = blockIdx.x;              // 0..63 (2 bt)
    int eq   = blockIdx.y;              // 0..7  (2 e = 16 ks)
    int tid  = threadIdx.x;
    int wv   = tid >> 6;                // 0..7
    int lane = tid & 63;
    int m    = lane & 15;
    int quad = lane >> 4;

    // ---- produce inputs: bt = btg*2 + (wv&1); jt = (wv>>1)*4 + q ----
    int pbt = wv & 1, jq = wv >> 1;
    short8 xfr[4];
    #pragma unroll
    for (int q = 0; q < 4; ++q)
        xfr[q] = *(const short8*)(xaf +
            (((size_t)(btg * 2 + pbt) * 16 + jq * 4 + q) * 64 + lane) * 8);

    const ushort* Ha0 = Hf + (size_t)(wv    ) * 128 * 512 + (size_t)lane * 8;
    const ushort* Ha1 = Hf + (size_t)(wv + 8) * 128 * 512 + (size_t)lane * 8;
    const ushort* Wl  = w2f + (size_t)lane * 8;

    short8 areg[4][2];                  // distance-4 A-ring, 2 it-streams
    floatx4 acc[2][2][2] = {};          // [t(it)][bb(bt)][oh]

    #define ALOAD(slot, s_)                                                   \
    {                                                                         \
        int ks_ = eq * 16 + (s_); if (ks_ > 127) ks_ = 127;                   \
        areg[slot][0] = *(const short8*)(Ha0 + (size_t)ks_ * 512);            \
        areg[slot][1] = *(const short8*)(Ha1 + (size_t)ks_ * 512);            \
    }
    // Verified jt-generic scatter: jp = jt>>1, qc = (jt&1)*2 + (quad>>1),
    // dp = (quad&1)*4  (bit-identical rounds 0-5).
    #define PRODUCE(buf, e_)                                                  \
    {                                                                         \
        short8 wf0 = *(const short8*)(Wl + (size_t)(e_) * 1024);              \
        short8 wf1 = *(const short8*)(Wl + (size_t)(e_) * 1024 + 512);        \
        _Pragma("unroll")                                                     \
        for (int q = 0; q < 4; ++q) {                                         \
            int jp = jq * 2 + (q >> 1);                                       \
            int qc = (q & 1) * 2 + (quad >> 1);                               \
            int dp = (quad & 1) * 4;                                          \
            floatx4 z = {0.f, 0.f, 0.f, 0.f};                                 \
            floatx4 d0 = MFMA16(xfr[q], wf0, z);                              \
            floatx4 d1 = MFMA16(xfr[q], wf1, z);                              \
            *(uint2*)&Bsl[buf][pbt][jp][0][(qc * 16 + m) * 8 + dp] = pack4(d0); \
            *(uint2*)&Bsl[buf][pbt][jp][1][(qc * 16 + m) * 8 + dp] = pack4(d1); \
        }                                                                     \
    }

    // prologue: fill ring s=0..3; produce window 0 into buf 0
    ALOAD(0, 0); ALOAD(1, 1); ALOAD(2, 2); ALOAD(3, 3);
    PRODUCE(0, eq * 2);
    BARRIER();

    #pragma unroll 1
    for (int w = 0; w < 2; ++w) {
        if (w == 0) PRODUCE(1, eq * 2 + 1);   // overlaps consume(0)
        #pragma unroll
        for (int kk = 0; kk < 8; ++kk) {      // slot = kk&3 (w*8 ≡ 0 mod 4)
            short8 a0 = areg[kk & 3][0];
            short8 a1 = areg[kk & 3][1];
            ALOAD(kk & 3, w * 8 + kk + 4);    // refill distance 4
            #pragma unroll
            for (int bb = 0; bb < 2; ++bb)
                #pragma unroll
                for (int oh = 0; oh < 2; ++oh) {
                    short8 b = *(const short8*)&Bsl[w & 1][bb][kk][oh][lane * 8];
                    acc[0][bb][oh] = MFMA16(a0, b, acc[0][bb][oh]);
                    acc[1][bb][oh] = MFMA16(a1, b, acc[1][bb][oh]);
                }
        }
        BARRIER();                      // A-ring stays in flight (lgkm only)
    }

    // ---- store f32 K-partials: Cp[bt][i][eq][o] ----
    #pragma unroll
    for (int t = 0; t < 2; ++t)
        #pragma unroll
        for (int bb = 0; bb < 2; ++bb)
            #pragma unroll
            for (int oh = 0; oh < 2; ++oh)
                #pragma unroll
                for (int r = 0; r < 4; ++r) {
                    int i = (wv + 8 * t) * 16 + quad * 4 + r;
                    int bt = btg * 2 + bb;
                    Cp[(((size_t)bt * NB + i) * 8 + eq) * FOUTN + oh * 16 + m]
                        = acc[t][bb][oh][r];
                }
    #undef ALOAD
    #undef PRODUCE
}

// ---------------------------------------------------------------------------
// epilogue (verified round-4 code; kqi loop 4 -> 8 for the new K-split):
// grid (128 bt, 2 ih) x 256 thr. out = gelu(sum_eq Cp + x@node_w + bias2).
// ---------------------------------------------------------------------------
__global__ __launch_bounds__(256) void epi_kernel(
        const ushort* __restrict__ xaf, const ushort* __restrict__ nwf,
        const float* __restrict__ bias2g, const float* __restrict__ Cp,
        float* __restrict__ out) {
    int bt   = blockIdx.x;
    int ih   = blockIdx.y;
    int tid  = threadIdx.x;
    int wv   = tid >> 6;
    int lane = tid & 63;
    int m    = lane & 15;
    int quad = lane >> 4;

    short8 nb0 = *(const short8*)(nwf + (size_t)lane * 8);
    short8 nb1 = *(const short8*)(nwf + ((size_t)64 + lane) * 8);

    #pragma unroll
    for (int t = 0; t < 2; ++t) {
        int it = ih * 8 + wv * 2 + t;
        short8 xa = *(const short8*)(xaf + (((size_t)bt * 16 + it) * 64 + lane) * 8);
        #pragma unroll
        for (int tn = 0; tn < 2; ++tn) {
            floatx4 z = {0.f, 0.f, 0.f, 0.f};
            floatx4 ea = MFMA16(xa, tn ? nb1 : nb0, z);
            float bz = bias2g[bt * 32 + tn * 16 + m];
            #pragma unroll
            for (int r = 0; r < 4; ++r) {
                int i = it * 16 + quad * 4 + r;
                float s = ea[r] + bz;
                #pragma unroll
                for (int kqi = 0; kqi < 8; ++kqi)
                    s += Cp[(((size_t)bt * NB + i) * 8 + kqi) * FOUTN + tn * 16 + m];
                out[((size_t)bt * NB + i) * FOUTN + tn * 16 + m] = gelu_f(s);
            }
        }
    }
}

// ---------------------------------------------------------------------------
extern "C" void kernel_launch(void* const* d_in, const int* in_sizes, int n_in,
                              void* d_out, int out_size, void* d_ws, size_t ws_size,
                              hipStream_t stream) {
    const float* x      = (const float*)d_in[0];
    const float* adj    = (const float*)d_in[1];
    const float* w1     = (const float*)d_in[2];
    const float* b1     = (const float*)d_in[3];
    const float* w2     = (const float*)d_in[4];
    const float* b2     = (const float*)d_in[5];
    const float* node_w = (const float*)d_in[6];
    const float* node_b = (const float*)d_in[7];
    float* out = (float*)d_out;

    // Workspace (~36.2 MiB):
    ushort* Hf     = (ushort*)d_ws;                  // 16*128*512  = 2 MiB
    ushort* w2f    = Hf + (size_t)16 * 128 * 512;    // 16*2*512    = 32 KiB
    ushort* xaf    = w2f + 16384;                    // 128*16*512  = 2 MiB
    ushort* nwf    = xaf + (size_t)128 * 16 * 512;   // 2*512       = 2 KiB
    float*  bias2g = (float*)(nwf + 1024);           // 128*32      = 16 KiB
    float*  Cp     = bias2g + 128 * 32;              // 128*256*8*32= 32 MiB

    hipLaunchKernelGGL(prep_kernel, dim3(289), dim3(256), 0, stream,
                       x, adj, w1, b1, w2, b2, node_w, node_b,
                       Hf, w2f, xaf, nwf, bias2g);
    hipLaunchKernelGGL(main_kernel, dim3(64, 8), dim3(512), 0, stream,
                       Hf, w2f, xaf, Cp);
    hipLaunchKernelGGL(epi_kernel, dim3(BT, 2), dim3(256), 0, stream,
                       xaf, nwf, bias2g, Cp, out);
}

// Round 7
// 107.327 us; speedup vs baseline: 1.0037x; 1.0037x over previous
//
#include <hip/hip_runtime.h>
#include <math.h>

// Problem constants
#define NB    256           // N nodes
#define FINN  32            // Fin
#define FOUTN 32            // Fout
#define BT    128           // B*T

// One GEMM: C[i,(bt,o)] = H[i,(e,j)] @ y2[(e,j),(bt,o)],  M=256 N=4096 K=4096.
// v7: back to ONE heavyweight fused kernel (R0's winning shape) at 4x the
// resident parallelism. Grid (128 bt, 8 ih) x 128 thr = 1024 blocks,
// 8 blocks/CU x 2 waves = 16 waves/CU. Per block: 2 i-tiles, full K in 32
// windows of 4 ks; y2 produced in-LDS (8x redundant, ~3us MFMA total — the
// price of zero inter-kernel handoff); Bs fragment-linear (conflict-free);
// A register-prefetched 1 window ahead; raw lgkm barriers keep global loads
// in flight. Epilogue fused. No Cp, no epilogue kernel.

typedef __attribute__((ext_vector_type(8))) short short8;   // 8 bf16 = 4 VGPRs
typedef __attribute__((ext_vector_type(4))) float floatx4;  // MFMA accumulator

#define MFMA16(a,b,c) __builtin_amdgcn_mfma_f32_16x16x32_bf16((a),(b),(c),0,0,0)

// LDS-ordering-only barrier: does NOT drain in-flight global register loads.
#define BARRIER() asm volatile("s_waitcnt lgkmcnt(0)\n\ts_barrier" ::: "memory")

__device__ __forceinline__ float gelu_f(float v) {
    return 0.5f * v * (1.0f + erff(v * 0.70710678118654752f));
}
__device__ __forceinline__ ushort f2bf(float x) {
    union { float f; unsigned u; } v; v.f = x;
    unsigned r = (v.u + 0x7FFFu + ((v.u >> 16) & 1u)) >> 16;
    return (ushort)r;
}
__device__ __forceinline__ uint2 pack4(floatx4 d) {
    uint2 p;
    p.x = (unsigned)f2bf(d[0]) | ((unsigned)f2bf(d[1]) << 16);
    p.y = (unsigned)f2bf(d[2]) | ((unsigned)f2bf(d[3]) << 16);
    return p;
}

// ---------------------------------------------------------------------------
// prep_kernel, grid 289 x 256 thr (verified rounds 2-6, verbatim):
//   [0,128):   Hf  = gelu(adj*w1+b1) in MFMA A-fragment order   (2 MiB)
//   [128,160): xaf = x in MFMA A-fragment order, bf16           (2 MiB)
//   [160,288): bias2g[bt][o] = node_b[o] + (sum_j x[bt,j,:]) @ b2
//   288:       w2f (B-frag order) + nwf (node_w B-frags)
// ---------------------------------------------------------------------------
__global__ __launch_bounds__(256) void prep_kernel(
        const float* __restrict__ x,   const float* __restrict__ adj,
        const float* __restrict__ w1,  const float* __restrict__ b1,
        const float* __restrict__ w2,  const float* __restrict__ b2,
        const float* __restrict__ node_w, const float* __restrict__ node_b,
        ushort* __restrict__ Hf, ushort* __restrict__ w2f,
        ushort* __restrict__ xaf, ushort* __restrict__ nwf,
        float* __restrict__ bias2g) {
    int bid = blockIdx.x;
    int tid = threadIdx.x;

    if (bid < 128) {                    // ---- Hf ----
        __shared__ float adjs[16][264];
        __shared__ float w1s[16], b1s[16];
        int it = bid & 15;
        int kq8 = bid >> 4;             // 0..7
        if (tid < 16) { w1s[tid] = w1[tid]; b1s[tid] = b1[tid]; }
        #pragma unroll
        for (int q = 0; q < 4; ++q) {
            int u = q * 256 + tid;
            int row = u >> 6, c4 = u & 63;
            *(float4*)&adjs[row][c4 * 4] =
                ((const float4*)(adj + ((size_t)it * 16 + row) * 256))[c4];
        }
        __syncthreads();
        #pragma unroll
        for (int q = 0; q < 4; ++q) {
            int u = q * 256 + tid;
            int ks = kq8 * 16 + (u >> 6);
            int lane = u & 63;
            int m = lane & 15, quad = lane >> 4;
            int e = ks >> 3;
            int j0 = (ks & 7) * 32 + quad * 8;
            float w = w1s[e], b = b1s[e];
            ushort tmp[8];
            #pragma unroll
            for (int d = 0; d < 8; ++d)
                tmp[d] = f2bf(gelu_f(adjs[m][j0 + d] * w + b));
            *(int4*)(Hf + (((size_t)it * 128 + ks) * 64 + lane) * 8) = *(int4*)tmp;
        }
        return;
    }
    if (bid < 160) {                    // ---- xaf: wave -> one bt ----
        int wv = tid >> 6, lane = tid & 63, m = lane & 15, quad = lane >> 4;
        int bt = (bid - 128) * 4 + wv;
        #pragma unroll
        for (int jt = 0; jt < 16; ++jt) {
            const float* xs = x + ((size_t)bt * NB + jt * 16 + m) * FINN + quad * 8;
            float4 lo = *(const float4*)xs;
            float4 hi = *(const float4*)(xs + 4);
            ushort tmp[8];
            tmp[0]=f2bf(lo.x); tmp[1]=f2bf(lo.y); tmp[2]=f2bf(lo.z); tmp[3]=f2bf(lo.w);
            tmp[4]=f2bf(hi.x); tmp[5]=f2bf(hi.y); tmp[6]=f2bf(hi.z); tmp[7]=f2bf(hi.w);
            *(int4*)(xaf + (((size_t)bt * 16 + jt) * 64 + lane) * 8) = *(int4*)tmp;
        }
        return;
    }
    if (bid < 288) {                    // ---- bias2g ----
        __shared__ float Sp[8][32];
        __shared__ float Svs[32];
        int bt = bid - 160;
        int f = tid & 31, grp = tid >> 5;
        float s = 0.f;
        for (int j = grp; j < NB; j += 8)
            s += x[((size_t)bt * NB + j) * FINN + f];
        Sp[grp][f] = s;
        __syncthreads();
        if (tid < 32) {
            float s2 = 0.f;
            #pragma unroll
            for (int g = 0; g < 8; ++g) s2 += Sp[g][tid];
            Svs[tid] = s2;
        }
        __syncthreads();
        if (tid < 32) {
            float bb = node_b[tid];
            #pragma unroll
            for (int f2 = 0; f2 < FINN; ++f2)
                bb += Svs[f2] * b2[f2 * FOUTN + tid];
            bias2g[bt * 32 + tid] = bb;
        }
        return;
    }
    // ---- bid == 288: w2f + nwf ----
    for (int s = 0; s < 2048; s += 256) {
        int slot = s + tid;             // (e*2+ot)*64 + lane
        int e = slot >> 7, r = slot & 127;
        int ot = r >> 6, lane = r & 63;
        int m = lane & 15, quad = lane >> 4;
        const float* src = w2 + (size_t)e * 1024 + (quad * 8) * 32 + ot * 16 + m;
        ushort tmp[8];
        #pragma unroll
        for (int i = 0; i < 8; ++i) tmp[i] = f2bf(src[i * 32]);
        *(int4*)(w2f + (size_t)slot * 8) = *(int4*)tmp;
    }
    if (tid < 128) {
        int ot = tid >> 6, lane = tid & 63, m = lane & 15, q = lane >> 4;
        ushort tmp[8];
        #pragma unroll
        for (int d = 0; d < 8; ++d)
            tmp[d] = f2bf(node_w[(q * 8 + d) * 32 + ot * 16 + m]);
        *(int4*)(nwf + tid * 8) = *(int4*)tmp;
    }
}

// ---------------------------------------------------------------------------
// fused_kernel: grid (128 bt, 8 ih) x 128 thr (2 waves), 8 blocks/CU.
// Per block: i-tiles {2ih, 2ih+1} (wave wv -> it = 2ih+wv), all 32 o, full K.
// 32 windows of 4 ks (window w: e = w>>1, h = w&1, ks = w*4+kk).
// Per window: ALOAD(w+1) 4 reg-prefetch, PRODUCE(w+1) 8 MFMA + 8 ds_write_b64
// into frag-linear dbuf Bsl, CONSUME(w) 8 ds_read_b128 + 8 MFMA, lgkm barrier.
// Produce role: wave wv makes frag kk = 2wv+c (c<2): jt = h*8+4wv+2c+d, both
// oh (verified scatter: qc=(jt&1)*2+(quad>>1), dp=(quad&1)*4). wr dbuf
// prefetched 2 e ahead. Epilogue: +x@node_w MFMA + bias2g, gelu, store.
// ---------------------------------------------------------------------------
__global__ __launch_bounds__(128, 4) void fused_kernel(
        const ushort* __restrict__ Hf,  const ushort* __restrict__ w2f,
        const ushort* __restrict__ xaf, const ushort* __restrict__ nwf,
        const float* __restrict__ bias2g, float* __restrict__ out) {
    __shared__ ushort Bsl[2][4][2][512];   // 16 KiB [buf][kk][oh][frag]

    int bt   = blockIdx.x;              // 0..127
    int ih   = blockIdx.y;              // 0..7
    int tid  = threadIdx.x;
    int wv   = tid >> 6;                // 0..1
    int lane = tid & 63;
    int m    = lane & 15;
    int quad = lane >> 4;
    int it   = ih * 2 + wv;             // wave's i-tile

    // produce inputs: xfr[h][c][d] = x A-frag for jt = h*8 + 4*wv + 2*c + d
    short8 xfr[2][2][2];
    #pragma unroll
    for (int h = 0; h < 2; ++h)
        #pragma unroll
        for (int c = 0; c < 2; ++c)
            #pragma unroll
            for (int d = 0; d < 2; ++d)
                xfr[h][c][d] = *(const short8*)(xaf +
                    (((size_t)bt * 16 + h * 8 + 4 * wv + 2 * c + d) * 64 + lane) * 8);

    const ushort* Ha = Hf + (size_t)it * 128 * 512 + (size_t)lane * 8;
    const ushort* Wl = w2f + (size_t)lane * 8;

    short8 areg[2][4];                  // 1-window A prefetch (ping-pong)
    short8 wr[2][2];                    // w2 frags [e&1][oh], 2-e prefetch
    floatx4 acc[2] = {};                // [oh]

    #define ALOADW(p, wnext)                                                  \
    {                                                                         \
        int ksb = (wnext) * 4;                                                \
        _Pragma("unroll")                                                     \
        for (int kk = 0; kk < 4; ++kk) {                                      \
            int ks = ksb + kk; if (ks > 127) ks = 127;                        \
            areg[p][kk] = *(const short8*)(Ha + (size_t)ks * 512);            \
        }                                                                     \
    }
    #define WLOAD(p, e_)                                                      \
    {                                                                         \
        int ec = (e_) > 15 ? 15 : (e_);                                       \
        wr[p][0] = *(const short8*)(Wl + (size_t)ec * 1024);                  \
        wr[p][1] = *(const short8*)(Wl + (size_t)ec * 1024 + 512);            \
    }
    // verified scatter (bit-identical rounds 0-6): frag slot kk = jsub&3,
    // qc = (jt&1)*2 + (quad>>1), dp = (quad&1)*4.
    #define PRODUCE(bp, hp, ep)                                               \
    {                                                                         \
        _Pragma("unroll")                                                     \
        for (int c = 0; c < 2; ++c) {                                         \
            int kk = 2 * wv + c;                                              \
            _Pragma("unroll")                                                 \
            for (int d = 0; d < 2; ++d) {                                     \
                int qc = d * 2 + (quad >> 1);                                 \
                int dp = (quad & 1) * 4;                                      \
                floatx4 z = {0.f, 0.f, 0.f, 0.f};                             \
                floatx4 d0 = MFMA16(xfr[hp][c][d], wr[ep][0], z);             \
                floatx4 d1 = MFMA16(xfr[hp][c][d], wr[ep][1], z);             \
                *(uint2*)&Bsl[bp][kk][0][(qc * 16 + m) * 8 + dp] = pack4(d0); \
                *(uint2*)&Bsl[bp][kk][1][(qc * 16 + m) * 8 + dp] = pack4(d1); \
            }                                                                 \
        }                                                                     \
    }
    #define CONSUME(bp, ap)                                                   \
    {                                                                         \
        _Pragma("unroll")                                                     \
        for (int kk = 0; kk < 4; ++kk) {                                      \
            short8 b0 = *(const short8*)&Bsl[bp][kk][0][lane * 8];            \
            short8 b1 = *(const short8*)&Bsl[bp][kk][1][lane * 8];            \
            acc[0] = MFMA16(areg[ap][kk], b0, acc[0]);                        \
            acc[1] = MFMA16(areg[ap][kk], b1, acc[1]);                        \
        }                                                                     \
    }

    // prologue: A(window 0), w2 e=0,1, produce window 0 (h=0,e=0) -> buf 0
    ALOADW(0, 0);
    WLOAD(0, 0);
    WLOAD(1, 1);
    PRODUCE(0, 0, 0);
    BARRIER();

    #pragma unroll 1
    for (int ww = 0; ww < 8; ++ww) {    // 4 windows per body, all static
        // window A (w=4ww, buf0): next = (h1, e=2ww -> wr[0])
        ALOADW(1, 4 * ww + 1);
        PRODUCE(1, 1, 0);
        CONSUME(0, 0);
        BARRIER();
        // window B (w=4ww+1, buf1): next = (h0, e=2ww+1 -> wr[1])
        ALOADW(0, 4 * ww + 2);
        PRODUCE(0, 0, 1);
        CONSUME(1, 1);
        WLOAD(0, 2 * ww + 2);           // refill wr[0] (used next-body A/D)
        BARRIER();
        // window C (w=4ww+2, buf0): next = (h1, e=2ww+1 -> wr[1])
        ALOADW(1, 4 * ww + 3);
        PRODUCE(1, 1, 1);
        CONSUME(0, 0);
        BARRIER();
        // window D (w=4ww+3, buf1): next = (h0, e=2ww+2 -> wr[0])
        ALOADW(0, 4 * ww + 4);          // clamped at ww=7 (unread)
        PRODUCE(0, 0, 0);               // window 32 at ww=7: unread, harmless
        CONSUME(1, 1);
        WLOAD(1, 2 * ww + 3);           // refill wr[1]
        BARRIER();
    }

    // ---- epilogue (verified): + x@node_w MFMA + bias2, gelu, store ----
    {
        short8 xa = *(const short8*)(xaf + (((size_t)bt * 16 + it) * 64 + lane) * 8);
        #pragma unroll
        for (int oh = 0; oh < 2; ++oh) {
            short8 nb = *(const short8*)(nwf + ((size_t)oh * 64 + lane) * 8);
            acc[oh] = MFMA16(xa, nb, acc[oh]);
            float bz = bias2g[bt * 32 + oh * 16 + m];
            #pragma unroll
            for (int r = 0; r < 4; ++r) {
                int i = it * 16 + quad * 4 + r;
                out[((size_t)bt * NB + i) * FOUTN + oh * 16 + m]
                    = gelu_f(acc[oh][r] + bz);
            }
        }
    }
    #undef ALOADW
    #undef WLOAD
    #undef PRODUCE
    #undef CONSUME
}

// ---------------------------------------------------------------------------
extern "C" void kernel_launch(void* const* d_in, const int* in_sizes, int n_in,
                              void* d_out, int out_size, void* d_ws, size_t ws_size,
                              hipStream_t stream) {
    const float* x      = (const float*)d_in[0];
    const float* adj    = (const float*)d_in[1];
    const float* w1     = (const float*)d_in[2];
    const float* b1     = (const float*)d_in[3];
    const float* w2     = (const float*)d_in[4];
    const float* b2     = (const float*)d_in[5];
    const float* node_w = (const float*)d_in[6];
    const float* node_b = (const float*)d_in[7];
    float* out = (float*)d_out;

    // Workspace (~4.2 MiB):
    ushort* Hf     = (ushort*)d_ws;                  // 16*128*512  = 2 MiB
    ushort* w2f    = Hf + (size_t)16 * 128 * 512;    // 16*2*512    = 32 KiB
    ushort* xaf    = w2f + 16384;                    // 128*16*512  = 2 MiB
    ushort* nwf    = xaf + (size_t)128 * 16 * 512;   // 2*512       = 2 KiB
    float*  bias2g = (float*)(nwf + 1024);           // 128*32      = 16 KiB

    hipLaunchKernelGGL(prep_kernel, dim3(289), dim3(256), 0, stream,
                       x, adj, w1, b1, w2, b2, node_w, node_b,
                       Hf, w2f, xaf, nwf, bias2g);
    hipLaunchKernelGGL(fused_kernel, dim3(BT, 8), dim3(128), 0, stream,
                       Hf, w2f, xaf, nwf, bias2g, out);
}

// Round 8
// 97.047 us; speedup vs baseline: 1.1100x; 1.1059x over previous
//
#include <hip/hip_runtime.h>
#include <math.h>

// Problem constants
#define NB    256           // N nodes
#define EDIM  16            // edge MLP hidden
#define FINN  32            // Fin
#define FOUTN 32            // Fout
#define BT    128           // B*T
#define KKD   4096          // GEMM K index: e*256 + j

typedef __attribute__((ext_vector_type(8))) short short8;   // 8 bf16 = 4 VGPRs
typedef __attribute__((ext_vector_type(4))) float floatx4;  // MFMA accumulator

#define MFMA16(a,b,c) __builtin_amdgcn_mfma_f32_16x16x32_bf16((a),(b),(c),0,0,0)

// Raw barrier: LDS ordering only — DOES NOT drain in-flight global register
// loads (vs __syncthreads' s_waitcnt vmcnt(0)). Safe here: Bs producer->
// consumer needs only lgkmcnt; A/W loads are wave-private and wait at use.
#define BARRIER() asm volatile("s_waitcnt lgkmcnt(0)\n\ts_barrier" ::: "memory")

__device__ __forceinline__ float gelu_f(float v) {
    return 0.5f * v * (1.0f + erff(v * 0.70710678118654752f));
}
__device__ __forceinline__ ushort f2bf(float x) {
    union { float f; unsigned u; } v; v.f = x;
    unsigned r = (v.u + 0x7FFFu + ((v.u >> 16) & 1u)) >> 16;
    return (ushort)r;
}
__device__ __forceinline__ float bf2f(ushort b) {
    union { unsigned u; float f; } v; v.u = ((unsigned)b) << 16; return v.f;
}
__device__ __forceinline__ uint2 pack4(floatx4 d) {
    uint2 p;
    p.x = (unsigned)f2bf(d[0]) | ((unsigned)f2bf(d[1]) << 16);
    p.y = (unsigned)f2bf(d[2]) | ((unsigned)f2bf(d[3]) << 16);
    return p;
}

// ---------------------------------------------------------------------------
// Prep (R0 verbatim): blocks [0,128): H in MFMA A-fragment order.
//       block 128:      w2 -> bf16 in MFMA B-fragment order.
// ---------------------------------------------------------------------------
__global__ __launch_bounds__(256) void h_kernel(const float* __restrict__ adj,
                                                const float* __restrict__ w1,
                                                const float* __restrict__ b1,
                                                const float* __restrict__ w2,
                                                ushort* __restrict__ Hf,
                                                ushort* __restrict__ w2f) {
    int tid = threadIdx.x;
    if (blockIdx.x >= 128) {
        for (int s = 0; s < 2048; s += 256) {
            int slot = s + tid;             // (e*2+ot)*64 + lane
            int e = slot >> 7, r = slot & 127;
            int ot = r >> 6, lane = r & 63;
            int m = lane & 15, quad = lane >> 4;
            const float* src = w2 + (size_t)e * 1024 + (quad * 8) * 32 + ot * 16 + m;
            ushort tmp[8];
            #pragma unroll
            for (int i = 0; i < 8; ++i) tmp[i] = f2bf(src[i * 32]);
            *(int4*)(w2f + (size_t)slot * 8) = *(int4*)tmp;
        }
        return;
    }
    __shared__ float adjs[16][264];
    __shared__ float w1s[16], b1s[16];
    int it = blockIdx.x & 15;
    int kq = blockIdx.x >> 4;               // 0..7
    if (tid < 16) { w1s[tid] = w1[tid]; b1s[tid] = b1[tid]; }
    #pragma unroll
    for (int q = 0; q < 4; ++q) {
        int u = q * 256 + tid;
        int row = u >> 6, c4 = u & 63;
        *(float4*)&adjs[row][c4 * 4] =
            ((const float4*)(adj + ((size_t)it * 16 + row) * 256))[c4];
    }
    __syncthreads();
    #pragma unroll
    for (int q = 0; q < 4; ++q) {
        int u = q * 256 + tid;              // 16 ks x 64 lanes
        int ks = kq * 16 + (u >> 6);
        int lane = u & 63;
        int m = lane & 15, quad = lane >> 4;
        int e = ks >> 3;
        int j0 = (ks & 7) * 32 + quad * 8;
        float w = w1s[e], b = b1s[e];
        ushort tmp[8];
        #pragma unroll
        for (int d = 0; d < 8; ++d)
            tmp[d] = f2bf(gelu_f(adjs[m][j0 + d] * w + b));
        *(int4*)(Hf + (((size_t)it * 128 + ks) * 64 + lane) * 8) = *(int4*)tmp;
    }
}

// ---------------------------------------------------------------------------
// Fused y2 + GEMM + epilogue — R0's measured-95us structure VERBATIM, with
// ONE change: Bs is fragment-linear (Bsl[buf][jp][oh][512]) instead of
// row-major [32][264], eliminating the counter-measured 3.3M-cycle
// SQ_LDS_BANK_CONFLICT. Produce scatter (jp=jt>>1, qc=(jt&1)*2+(quad>>1),
// dp=(quad&1)*4) and consume (lane*16B) are the R1-R7 end-to-end-verified
// fragment formulas; accumulation order is bit-identical to R0.
// ---------------------------------------------------------------------------
#define NCH  16
#define XBP  40    // xb/nwT padded row (bf16)

__global__ __launch_bounds__(256, 2) void fused_kernel(
        const float* __restrict__ x,      const ushort* __restrict__ w2f,
        const float* __restrict__ b2,     const float* __restrict__ node_w,
        const float* __restrict__ node_b, const ushort* __restrict__ Hf,
        float* __restrict__ out) {
    __shared__ ushort xb[NB][XBP];        // 20 KiB   x[bt] in bf16
    __shared__ ushort Bsl[2][8][2][512];  // 32 KiB   y2 chunk dbuf, frag-linear
    __shared__ ushort nwT[32][XBP];       // 2.5 KiB  node_w^T in bf16
    __shared__ float  Sp[8][32];
    __shared__ float  Sv[32];
    __shared__ float  bias2[32];

    int bt   = blockIdx.x;              // 0..127
    int iq   = blockIdx.y;              // 0..3
    int tid  = threadIdx.x;
    int wv   = tid >> 6;                // 0..3
    int lane = tid & 63;
    int m    = lane & 15;
    int quad = lane >> 4;
    int it   = iq * 4 + wv;             // wave's i-tile (16 rows)
    int i0g  = it * 16;

    const ushort* Hlane = Hf + (size_t)it * 128 * 512 + lane * 8;
    const ushort* Wlane = w2f + (size_t)lane * 8;

    short8 areg[2][8];                  // A-frag ping-pong
    short8 wreg[2][2];                  // w2-frag ping-pong (both o-halves)

    #define ALOAD(dst, c)                                                     \
    {                                                                         \
        _Pragma("unroll")                                                     \
        for (int kk = 0; kk < 8; ++kk)                                        \
            dst[kk] = *(const short8*)(Hlane + ((c) * 8 + kk) * 512);         \
    }
    #define WLOADB(dst, e)                                                    \
    {                                                                         \
        dst[0] = *(const short8*)(Wlane + (size_t)(e) * 1024);                \
        dst[1] = *(const short8*)(Wlane + (size_t)(e) * 1024 + 512);          \
    }

    WLOADB(wreg[0], 0);                 // chunk-0 w2 frags (used after staging)

    // ---- stage xb (bf16) + nwT ----
    const float4* xg = (const float4*)(x + (size_t)bt * NB * FINN);
    #pragma unroll
    for (int itr = 0; itr < 8; ++itr) {
        int idx4 = itr * 256 + tid;
        float4 v = xg[idx4];
        int j = idx4 >> 3, f = (idx4 & 7) * 4;
        uint2 p;
        p.x = (unsigned)f2bf(v.x) | ((unsigned)f2bf(v.y) << 16);
        p.y = (unsigned)f2bf(v.z) | ((unsigned)f2bf(v.w) << 16);
        *(uint2*)&xb[j][f] = p;
    }
    {
        float4 v = ((const float4*)node_w)[tid];
        int f = tid >> 3, o = (tid & 7) * 4;
        nwT[o + 0][f] = f2bf(v.x); nwT[o + 1][f] = f2bf(v.y);
        nwT[o + 2][f] = f2bf(v.z); nwT[o + 3][f] = f2bf(v.w);
    }
    __syncthreads();

    {   // S partials
        int f = tid & 31, grp = tid >> 5;
        float s = 0.f;
        for (int j = grp * 32; j < grp * 32 + 32; ++j) s += bf2f(xb[j][f]);
        Sp[grp][f] = s;
    }

    // production A-frags: wave's 4 j-tiles
    short8 afr[4];
    #pragma unroll
    for (int t = 0; t < 4; ++t)
        afr[t] = *(short8*)&xb[(wv * 4 + t) * 16 + m][quad * 8];

    __syncthreads();
    if (tid < 32) {                     // Sv: written+read by wave 0 only
        float s = 0.f;
        #pragma unroll
        for (int g = 0; g < 8; ++g) s += Sp[g][tid];
        Sv[tid] = s;
    }

    floatx4 acc[2] = {};

    // produce chunk into Bsl[buf]: fragment-linear (verified R1-R7 scatter)
    #define PRODUCE(buf, w)                                                   \
    {                                                                         \
        _Pragma("unroll")                                                     \
        for (int t = 0; t < 4; ++t) {                                         \
            floatx4 z = {0.f, 0.f, 0.f, 0.f};                                 \
            floatx4 d0 = MFMA16(afr[t], w[0], z);                             \
            floatx4 d1 = MFMA16(afr[t], w[1], z);                             \
            int jt = wv * 4 + t;                                              \
            int jp = jt >> 1;                                                 \
            int qc = (jt & 1) * 2 + (quad >> 1);                              \
            int dp = (quad & 1) * 4;                                          \
            *(uint2*)&Bsl[buf][jp][0][(qc * 16 + m) * 8 + dp] = pack4(d0);    \
            *(uint2*)&Bsl[buf][jp][1][(qc * 16 + m) * 8 + dp] = pack4(d1);    \
        }                                                                     \
    }
    #define GEMMC(buf, ar)                                                    \
    {                                                                         \
        _Pragma("unroll")                                                     \
        for (int kk = 0; kk < 8; ++kk) {                                      \
            short8 b0 = *(const short8*)&Bsl[buf][kk][0][lane * 8];           \
            short8 b1 = *(const short8*)&Bsl[buf][kk][1][lane * 8];           \
            acc[0] = MFMA16(ar[kk], b0, acc[0]);                              \
            acc[1] = MFMA16(ar[kk], b1, acc[1]);                              \
        }                                                                     \
    }

    #pragma unroll
    for (int c = 0; c < NCH; ++c) {
        ALOAD(areg[c & 1], c);                        // consumed window c+1
        if (c < NCH - 1) WLOADB(wreg[(c + 1) & 1], c + 1);
        PRODUCE(c & 1, wreg[c & 1]);                  // w-frags from window c-1
        if (c > 0) {
            GEMMC((c - 1) & 1, areg[(c - 1) & 1]);
        } else if (tid < 32) {                        // slack in window 0
            float bb = node_b[tid];
            #pragma unroll
            for (int f = 0; f < FINN; ++f) bb += Sv[f] * b2[f * FOUTN + tid];
            bias2[tid] = bb;
        }
        BARRIER();                                    // no vmcnt(0) drain
    }
    GEMMC((NCH - 1) & 1, areg[(NCH - 1) & 1]);        // final window

    // ---- epilogue: + x@node_w (1 MFMA/tile) + bias2, gelu, store ----
    {
        short8 xa = *(short8*)&xb[i0g + m][quad * 8];
        #pragma unroll
        for (int tn = 0; tn < 2; ++tn) {
            short8 nb = *(short8*)&nwT[tn * 16 + m][quad * 8];
            acc[tn] = MFMA16(xa, nb, acc[tn]);
        }
    }
    #pragma unroll
    for (int tn = 0; tn < 2; ++tn) {
        int o = tn * 16 + m;
        float bz = bias2[o];
        #pragma unroll
        for (int r = 0; r < 4; ++r) {
            int row = i0g + quad * 4 + r;
            out[((size_t)bt * NB + row) * FOUTN + o] = gelu_f(acc[tn][r] + bz);
        }
    }
    #undef ALOAD
    #undef WLOADB
    #undef PRODUCE
    #undef GEMMC
}

// ---------------------------------------------------------------------------
extern "C" void kernel_launch(void* const* d_in, const int* in_sizes, int n_in,
                              void* d_out, int out_size, void* d_ws, size_t ws_size,
                              hipStream_t stream) {
    const float* x      = (const float*)d_in[0];
    const float* adj    = (const float*)d_in[1];
    const float* w1     = (const float*)d_in[2];
    const float* b1     = (const float*)d_in[3];
    const float* w2     = (const float*)d_in[4];
    const float* b2     = (const float*)d_in[5];
    const float* node_w = (const float*)d_in[6];
    const float* node_b = (const float*)d_in[7];
    float* out = (float*)d_out;

    ushort* Hf  = (ushort*)d_ws;                 // 2 MiB, A-fragment order
    ushort* w2f = Hf + (size_t)NB * KKD;         // 32 KiB, B-fragment order

    hipLaunchKernelGGL(h_kernel, dim3(129), dim3(256), 0, stream,
                       adj, w1, b1, w2, Hf, w2f);
    hipLaunchKernelGGL(fused_kernel, dim3(BT, 4), dim3(256), 0, stream,
                       x, w2f, b2, node_w, node_b, Hf, out);
}